// Round 2
// baseline (206.809 us; speedup 1.0000x reference)
//
#include <hip/hip_runtime.h>
#include <float.h>

// x: (B=64, C=256, H=64, W=64) fp32; top-8 per batch over C*H*W; out [B,8,C+3].
#define BB    64
#define CC    256
#define HH    64
#define WW    64
#define K     8
#define NPB   (CC * HH * WW)        // 1048576 elems/batch
#define TPB   256
#define OUTC  (CC + 3)              // 259
#define NBLK  32                    // filter/partial blocks per batch
#define CHUNK (NPB / NBLK)          // 32768
#define VECS  (CHUNK / (TPB * 4))   // 32 float4 per thread
#define CAP   4096                  // candidate slots per batch (expected ~512)
#define SCH   16                    // sample: 16 chunks of 256 float4 per batch

// ---------- shared helpers ----------

// Total order matching lax.top_k: larger value wins; ties -> lower index wins.
__device__ __forceinline__ bool cand_gt(float v1, int i1, float v2, int i2) {
    return (v1 > v2) || (v1 == v2 && i1 < i2);
}

__device__ __forceinline__ void insert8(float nv, int ni, float (&v)[K], int (&ix)[K]) {
    bool gt[K];
#pragma unroll
    for (int p = 0; p < K; ++p) gt[p] = cand_gt(nv, ni, v[p], ix[p]);
#pragma unroll
    for (int p = K - 1; p > 0; --p) {
        if (gt[p - 1]) { v[p] = v[p - 1]; ix[p] = ix[p - 1]; }
    }
#pragma unroll
    for (int p = 0; p < K; ++p) {
        if (gt[p] && (p == 0 || !gt[p - 1])) { v[p] = nv; ix[p] = ni; }
    }
}

// value-only variant (for the threshold sample; ties irrelevant there)
__device__ __forceinline__ void insertv8(float nv, float (&v)[K]) {
    bool gt[K];
#pragma unroll
    for (int p = 0; p < K; ++p) gt[p] = (nv > v[p]);
#pragma unroll
    for (int p = K - 1; p > 0; --p) {
        if (gt[p - 1]) v[p] = v[p - 1];
    }
#pragma unroll
    for (int p = 0; p < K; ++p) {
        if (gt[p] && (p == 0 || !gt[p - 1])) v[p] = nv;
    }
}

// Merge my sorted-8 with partner lane's (shfl_xor d), keep top-8 descending.
__device__ __forceinline__ void merge_shfl(int d, float (&v)[K], int (&ix)[K]) {
    float ov[K]; int oi[K];
#pragma unroll
    for (int p = 0; p < K; ++p) {
        ov[p] = __shfl_xor(v[p], d, 64);
        oi[p] = __shfl_xor(ix[p], d, 64);
    }
    float mv[K]; int mi[K];
#pragma unroll
    for (int p = 0; p < K; ++p) {
        bool a = cand_gt(v[p], ix[p], ov[K - 1 - p], oi[K - 1 - p]);
        mv[p] = a ? v[p] : ov[K - 1 - p];
        mi[p] = a ? ix[p] : oi[K - 1 - p];
    }
#pragma unroll
    for (int dd = 4; dd >= 1; dd >>= 1) {
#pragma unroll
        for (int i = 0; i < K; ++i) {
            if ((i & dd) == 0) {
                int j = i + dd;
                if (cand_gt(mv[j], mi[j], mv[i], mi[i])) {
                    float tv = mv[i]; mv[i] = mv[j]; mv[j] = tv;
                    int   ti = mi[i]; mi[i] = mi[j]; mi[j] = ti;
                }
            }
        }
    }
#pragma unroll
    for (int p = 0; p < K; ++p) { v[p] = mv[p]; ix[p] = mi[p]; }
}

__device__ __forceinline__ void merge_shfl_v(int d, float (&v)[K]) {
    float ov[K];
#pragma unroll
    for (int p = 0; p < K; ++p) ov[p] = __shfl_xor(v[p], d, 64);
    float mv[K];
#pragma unroll
    for (int p = 0; p < K; ++p) mv[p] = fmaxf(v[p], ov[K - 1 - p]);
#pragma unroll
    for (int dd = 4; dd >= 1; dd >>= 1) {
#pragma unroll
        for (int i = 0; i < K; ++i) {
            if ((i & dd) == 0) {
                int j = i + dd;
                float lo = fminf(mv[i], mv[j]);
                mv[i] = fmaxf(mv[i], mv[j]);
                mv[j] = lo;
            }
        }
    }
#pragma unroll
    for (int p = 0; p < K; ++p) v[p] = mv[p];
}

// ---------- fast path: sample -> filter -> select ----------

// Per-batch threshold = 8th largest of a 16384-element subset (provably <=
// 8th largest of the full set, so no true top-8 element is filtered out).
__global__ __launch_bounds__(TPB) void sample_thresh(const float* __restrict__ x,
                                                     float* __restrict__ thr) {
    const int b = blockIdx.x;
    const int t = threadIdx.x;
    float v[K];
#pragma unroll
    for (int p = 0; p < K; ++p) v[p] = -FLT_MAX;

    const float* xb = x + (size_t)b * NPB;
#pragma unroll
    for (int c = 0; c < SCH; ++c) {
        const int f4 = c * 16384 + t;           // coalesced 4KB chunk per wave-iter
        const float4 f = *reinterpret_cast<const float4*>(xb + (size_t)f4 * 4);
        if (f.x > v[K - 1]) insertv8(f.x, v);
        if (f.y > v[K - 1]) insertv8(f.y, v);
        if (f.z > v[K - 1]) insertv8(f.z, v);
        if (f.w > v[K - 1]) insertv8(f.w, v);
    }

    __shared__ float sv[TPB * K];
#pragma unroll
    for (int p = 0; p < K; ++p) sv[p * TPB + t] = v[p];
    __syncthreads();

    if (t < 64) {
        float mv[K];
#pragma unroll
        for (int p = 0; p < K; ++p) mv[p] = -FLT_MAX;
        for (int j = t; j < TPB * K; j += 64) {
            if (sv[j] > mv[K - 1]) insertv8(sv[j], mv);
        }
        merge_shfl_v(1, mv);  merge_shfl_v(2, mv);  merge_shfl_v(4, mv);
        merge_shfl_v(8, mv);  merge_shfl_v(16, mv); merge_shfl_v(32, mv);
        if (t == 0) thr[b] = mv[K - 1];
    }
}

// Stream all data; append (val,idx) >= T_b to per-batch candidate buffer.
__global__ __launch_bounds__(TPB) void filter_cand(const float* __restrict__ x,
                                                   const float* __restrict__ thr,
                                                   float* __restrict__ cval,
                                                   int* __restrict__ cidx,
                                                   int* __restrict__ cnt) {
    const int b   = blockIdx.x / NBLK;
    const int blk = blockIdx.x % NBLK;
    const int t   = threadIdx.x;
    const float T = thr[b];                      // block-uniform -> scalarized
    const float* xb = x + (size_t)b * NPB + (size_t)blk * CHUNK;
    const int base = blk * CHUNK;

#pragma unroll 4
    for (int it = 0; it < VECS; ++it) {
        const int e = (it * TPB + t) * 4;
        const float4 f = *reinterpret_cast<const float4*>(xb + e);
        const float m = fmaxf(fmaxf(f.x, f.y), fmaxf(f.z, f.w));
        if (m >= T) {                            // rare: ~1/512 per lane-iter
            const float vals[4] = {f.x, f.y, f.z, f.w};
#pragma unroll
            for (int j = 0; j < 4; ++j) {
                if (vals[j] >= T) {
                    const int o = atomicAdd(&cnt[b], 1);
                    if (o < CAP) {
                        cval[(size_t)b * CAP + o] = vals[j];
                        cidx[(size_t)b * CAP + o] = base + e + j;
                    }
                }
            }
        }
    }
}

// Exact top-8 (value desc, index-asc tiebreak) over <=CAP candidates; emit rows.
__global__ __launch_bounds__(TPB) void final_select(const float* __restrict__ cval,
                                                    const int* __restrict__ cidx,
                                                    const int* __restrict__ cnt,
                                                    float* __restrict__ out) {
    const int b = blockIdx.x;
    const int t = threadIdx.x;
    const int n = min(cnt[b], CAP);

    float v[K]; int ix[K];
#pragma unroll
    for (int p = 0; p < K; ++p) { v[p] = -FLT_MAX; ix[p] = 0x7fffffff; }
    const float* cv = cval + (size_t)b * CAP;
    const int*   ci = cidx + (size_t)b * CAP;
    for (int j = t; j < n; j += TPB) {
        const float nv = cv[j]; const int ni = ci[j];
        if (cand_gt(nv, ni, v[K - 1], ix[K - 1])) insert8(nv, ni, v, ix);
    }

    // zero this batch's output block (d_out is poisoned)
    float* ob = out + (size_t)b * K * OUTC;
    for (int j = t; j < K * OUTC; j += TPB) ob[j] = 0.0f;

    __shared__ float sv[TPB * K];
    __shared__ int   si[TPB * K];
#pragma unroll
    for (int p = 0; p < K; ++p) { sv[p * TPB + t] = v[p]; si[p * TPB + t] = ix[p]; }
    __syncthreads();

    if (t < 64) {
        float mv[K]; int mi[K];
#pragma unroll
        for (int p = 0; p < K; ++p) { mv[p] = -FLT_MAX; mi[p] = 0x7fffffff; }
        for (int j = t; j < TPB * K; j += 64) {
            const float nv = sv[j]; const int ni = si[j];
            if (cand_gt(nv, ni, mv[K - 1], mi[K - 1])) insert8(nv, ni, mv, mi);
        }
        merge_shfl(1, mv, mi);  merge_shfl(2, mv, mi);  merge_shfl(4, mv, mi);
        merge_shfl(8, mv, mi);  merge_shfl(16, mv, mi); merge_shfl(32, mv, mi);
        if (t == 0) {
#pragma unroll
            for (int r = 0; r < K; ++r) {
                const int idx = mi[r];
                const int c   = idx >> 12;       // /4096
                const int rem = idx & 4095;
                const int yy  = rem >> 6;
                const int xx  = rem & 63;
                float* row = ob + r * OUTC;
                row[c]      = 1.0f;
                row[CC]     = mv[r];
                row[CC + 1] = (float)xx / 63.0f;
                row[CC + 2] = (float)yy / 63.0f;
            }
        }
    }
}

// ---------- fallback path (R1 working version, used if ws too small) ----------

__global__ __launch_bounds__(TPB) void topk_partial(const float* __restrict__ x,
                                                    float* __restrict__ wval,
                                                    int* __restrict__ widx) {
    const int b   = blockIdx.x / NBLK;
    const int blk = blockIdx.x % NBLK;
    const int t   = threadIdx.x;
    const float* xb = x + (size_t)b * NPB + (size_t)blk * CHUNK;
    const int base = blk * CHUNK;

    float v[K]; int ix[K];
#pragma unroll
    for (int p = 0; p < K; ++p) { v[p] = -FLT_MAX; ix[p] = 0x7fffffff; }

#pragma unroll 2
    for (int it = 0; it < VECS; ++it) {
        const int e = (it * TPB + t) * 4;
        const float4 f = *reinterpret_cast<const float4*>(xb + e);
        const float vals[4] = {f.x, f.y, f.z, f.w};
#pragma unroll
        for (int j = 0; j < 4; ++j) {
            if (vals[j] > v[K - 1]) insert8(vals[j], base + e + j, v, ix);
        }
    }

    __shared__ float sv[TPB * K];
    __shared__ int   si[TPB * K];
#pragma unroll
    for (int p = 0; p < K; ++p) { sv[p * TPB + t] = v[p]; si[p * TPB + t] = ix[p]; }
    __syncthreads();

    if (t < 64) {
        float mv[K]; int mi[K];
#pragma unroll
        for (int p = 0; p < K; ++p) { mv[p] = -FLT_MAX; mi[p] = 0x7fffffff; }
        for (int j = t; j < TPB * K; j += 64) {
            const float nv = sv[j]; const int ni = si[j];
            if (cand_gt(nv, ni, mv[K - 1], mi[K - 1])) insert8(nv, ni, mv, mi);
        }
        merge_shfl(1, mv, mi);  merge_shfl(2, mv, mi);  merge_shfl(4, mv, mi);
        merge_shfl(8, mv, mi);  merge_shfl(16, mv, mi); merge_shfl(32, mv, mi);
        if (t == 0) {
            const int ob = blockIdx.x * K;
#pragma unroll
            for (int p = 0; p < K; ++p) { wval[ob + p] = mv[p]; widx[ob + p] = mi[p]; }
        }
    }
}

__global__ __launch_bounds__(TPB) void topk_final(const float* __restrict__ wval,
                                                  const int* __restrict__ widx,
                                                  float* __restrict__ out) {
    const int b = blockIdx.x;
    const int t = threadIdx.x;

    __shared__ float sv[NBLK * K];
    __shared__ int   si[NBLK * K];
    sv[t] = wval[(size_t)b * NBLK * K + t];
    si[t] = widx[(size_t)b * NBLK * K + t];

    float* ob = out + (size_t)b * K * OUTC;
    for (int j = t; j < K * OUTC; j += TPB) ob[j] = 0.0f;
    __syncthreads();

    __shared__ float rv[TPB];
    __shared__ int   ri[TPB];
    __shared__ int   rp[TPB];

    for (int r = 0; r < K; ++r) {
        rv[t] = sv[t]; ri[t] = si[t]; rp[t] = t;
        __syncthreads();
#pragma unroll
        for (int s = TPB / 2; s > 0; s >>= 1) {
            if (t < s) {
                if (cand_gt(rv[t + s], ri[t + s], rv[t], ri[t])) {
                    rv[t] = rv[t + s]; ri[t] = ri[t + s]; rp[t] = rp[t + s];
                }
            }
            __syncthreads();
        }
        if (t == 0) {
            const float val = rv[0];
            const int   idx = ri[0];
            sv[rp[0]] = -FLT_MAX;
            si[rp[0]] = 0x7fffffff;
            const int c   = idx >> 12;
            const int rem = idx & 4095;
            const int yy  = rem >> 6;
            const int xx  = rem & 63;
            float* row = ob + r * OUTC;
            row[c]      = 1.0f;
            row[CC]     = val;
            row[CC + 1] = (float)xx / 63.0f;
            row[CC + 2] = (float)yy / 63.0f;
        }
        __syncthreads();
    }
}

// ---------- launch ----------

extern "C" void kernel_launch(void* const* d_in, const int* in_sizes, int n_in,
                              void* d_out, int out_size, void* d_ws, size_t ws_size,
                              hipStream_t stream) {
    const float* x = (const float*)d_in[0];
    float* out = (float*)d_out;

    // fast-path ws layout:
    //   cval: BB*CAP floats (1 MB)  @ 0
    //   cidx: BB*CAP ints   (1 MB)  @ 1 MB
    //   cnt:  BB ints               @ 2 MB
    //   thr:  BB floats             @ 2 MB + 256
    const size_t need = (size_t)BB * CAP * 8 + 512;
    if (ws_size >= need) {
        float* cval = (float*)d_ws;
        int*   cidx = (int*)((char*)d_ws + (size_t)BB * CAP * sizeof(float));
        int*   cnt  = (int*)((char*)d_ws + (size_t)BB * CAP * 8);
        float* thr  = (float*)((char*)cnt + 256);

        hipMemsetAsync(cnt, 0, BB * sizeof(int), stream);
        sample_thresh<<<BB, TPB, 0, stream>>>(x, thr);
        filter_cand<<<BB * NBLK, TPB, 0, stream>>>(x, thr, cval, cidx, cnt);
        final_select<<<BB, TPB, 0, stream>>>(cval, cidx, cnt, out);
    } else {
        float* wval = (float*)d_ws;
        int*   widx = (int*)((char*)d_ws + (size_t)BB * NBLK * K * sizeof(float));
        topk_partial<<<BB * NBLK, TPB, 0, stream>>>(x, wval, widx);
        topk_final<<<BB, TPB, 0, stream>>>(wval, widx, out);
    }
}